// Round 4
// baseline (295.684 us; speedup 1.0000x reference)
//
#include <hip/hip_runtime.h>
#include <math.h>

#define NPTS 2048
#define BATCH 16
#define KNN 16
#define HID 128
#define RPB 8          // rows (queries) per block = waves per block
#define CAP 128        // compacted-candidate capacity per wave

// ---------------------------------------------------------------------------
// kNN via threshold selection. One wave per query row. (Unchanged from R1.)
// ---------------------------------------------------------------------------
__global__ __launch_bounds__(512) void knn_kernel(const float* __restrict__ pc,
                                                  int* __restrict__ nbr)
{
    __shared__ __align__(16) float4 pts[NPTS];        // x,y,z,|p|^2  (32 KB)
    __shared__ unsigned ckey[RPB][CAP];               // 4 KB
    __shared__ unsigned cidx[RPB][CAP];               // 4 KB

    const int b = blockIdx.x >> 8;                    // 256 blocks per batch
    const int rblk = blockIdx.x & 255;
    const float* p = pc + (size_t)b * NPTS * 3;

    for (int t = threadIdx.x; t < NPTS; t += 512) {
        float x = p[t * 3 + 0], y = p[t * 3 + 1], z = p[t * 3 + 2];
        pts[t] = make_float4(x, y, z, x * x + y * y + z * z);
    }
    __syncthreads();

    const int w = threadIdx.x >> 6;
    const int lane = threadIdx.x & 63;
    const int i = rblk * RPB + w;                     // query row in batch
    const float4 pi = pts[i];

    unsigned key[32];
    #pragma unroll
    for (int t = 0; t < 32; ++t) {
        float4 c = pts[t * 64 + lane];
        float dot = fmaf(pi.x, c.x, fmaf(pi.y, c.y, pi.z * c.z));
        float d2 = fmaf(-2.0f, dot, pi.w + c.w);
        key[t] = __float_as_uint(d2 + 16.0f);
    }

    unsigned km = 0xFFFFFFFFu;
    #pragma unroll
    for (int t = 0; t < 32; ++t) km = min(km, key[t]);

    unsigned v = km;
    #pragma unroll
    for (int k = 2; k <= 64; k <<= 1) {
        #pragma unroll
        for (int j = k >> 1; j > 0; j >>= 1) {
            unsigned o = (unsigned)__shfl_xor((int)v, j, 64);
            bool up = ((lane & k) == 0);
            bool lower = ((lane & j) == 0);
            unsigned mn = min(v, o), mx = max(v, o);
            v = (up == lower) ? mn : mx;
        }
    }
    const unsigned T0 = (unsigned)__shfl((int)v, 15, 64);

    unsigned base = 0;
    #pragma unroll 1
    for (int t = 0; t < 32; ++t) {
        bool pred = key[t] <= T0;
        unsigned long long mask = __ballot(pred);
        if (mask) {
            unsigned prefix = __builtin_amdgcn_mbcnt_hi(
                (unsigned)(mask >> 32),
                __builtin_amdgcn_mbcnt_lo((unsigned)mask, 0));
            unsigned pos = base + prefix;
            if (pred && pos < CAP) {
                ckey[w][pos] = key[t];
                cidx[w][pos] = (unsigned)(t * 64 + lane);
            }
            base += (unsigned)__popcll(mask);
        }
    }
    __threadfence_block();
    const int m = (int)base;

    int* out = nbr + ((size_t)b * NPTS + i) * KNN;

    if (m <= CAP) {
        unsigned k0 = (lane < m) ? ckey[w][lane] : 0xFFFFFFFFu;
        unsigned k1 = (lane + 64 < m) ? ckey[w][lane + 64] : 0xFFFFFFFFu;
        int r0 = 0, r1 = 0;
        if (m <= 64) {
            #pragma unroll 1
            for (int jj = 0; jj < m; ++jj) {
                unsigned kj = ckey[w][jj];
                r0 += (kj < k0) || (kj == k0 && jj < lane);
            }
        } else {
            #pragma unroll 1
            for (int jj = 0; jj < m; ++jj) {
                unsigned kj = ckey[w][jj];
                r0 += (kj < k0) || (kj == k0 && jj < lane);
                r1 += (kj < k1) || (kj == k1 && jj < lane + 64);
            }
        }
        if (lane < m && r0 < KNN) out[r0] = (int)cidx[w][lane];
        if (lane + 64 < m && r1 < KNN) out[r1] = (int)cidx[w][lane + 64];
    } else {
        unsigned T = 0;
        #pragma unroll 1
        for (int bit = 31; bit >= 0; --bit) {
            unsigned trial = T | (1u << bit);
            int cnt = 0;
            #pragma unroll
            for (int t = 0; t < 32; ++t) cnt += (key[t] < trial);
            #pragma unroll
            for (int off = 32; off; off >>= 1)
                cnt += __shfl_xor(cnt, off, 64);
            if (cnt < KNN) T = trial;
        }
        unsigned bs = 0;
        #pragma unroll 1
        for (int t = 0; t < 32; ++t) {
            bool p1 = key[t] < T;
            unsigned long long mask = __ballot(p1);
            if (mask) {
                unsigned prefix = __builtin_amdgcn_mbcnt_hi(
                    (unsigned)(mask >> 32),
                    __builtin_amdgcn_mbcnt_lo((unsigned)mask, 0));
                if (p1) out[bs + prefix] = t * 64 + lane;
                bs += (unsigned)__popcll(mask);
            }
        }
        #pragma unroll 1
        for (int t = 0; t < 32 && bs < KNN; ++t) {
            bool p2 = key[t] == T;
            unsigned long long mask = __ballot(p2);
            if (mask) {
                unsigned prefix = __builtin_amdgcn_mbcnt_hi(
                    (unsigned)(mask >> 32),
                    __builtin_amdgcn_mbcnt_lo((unsigned)mask, 0));
                unsigned pos = bs + prefix;
                if (p2 && pos < KNN) out[pos] = t * 64 + lane;
                bs += (unsigned)__popcll(mask);
            }
        }
    }
}

// ---------------------------------------------------------------------------
// Layer 1: 3 -> 128, fused gather+matvec+bias+relu. One block per point.
// ---------------------------------------------------------------------------
__global__ __launch_bounds__(128) void layer1_kernel(
    const float* __restrict__ pc, const int* __restrict__ nbr,
    const float* __restrict__ W1r, const float* __restrict__ b1,
    const float* __restrict__ W1s, float* __restrict__ x1)
{
    __shared__ float agg[3], xi[3];
    __shared__ float nb[KNN][3];
    const int p = blockIdx.x;                   // global point id
    const int b = p >> 11;
    const float* pcb = pc + ((size_t)b << 11) * 3;
    const int h = threadIdx.x;
    if (h < KNN) {
        int j = nbr[(size_t)p * KNN + h];
        nb[h][0] = pcb[j * 3 + 0];
        nb[h][1] = pcb[j * 3 + 1];
        nb[h][2] = pcb[j * 3 + 2];
    }
    if (h >= KNN && h < KNN + 3) {
        int c = h - KNN;
        xi[c] = pc[(size_t)p * 3 + c];
    }
    __syncthreads();
    if (h < 3) {
        float s = 0.f;
        #pragma unroll
        for (int t = 0; t < KNN; ++t) s += nb[t][h];
        agg[h] = s;
    }
    __syncthreads();
    float acc = b1[h];
    #pragma unroll
    for (int c = 0; c < 3; ++c)
        acc += W1r[h * 3 + c] * agg[c] + W1s[h * 3 + c] * xi[c];
    x1[(size_t)p * HID + h] = fmaxf(acc, 0.f);
}

// ---------------------------------------------------------------------------
// Gather-sum, float4-vectorized: thread (p, c4) sums 16 neighbor rows.
// ---------------------------------------------------------------------------
__global__ __launch_bounds__(256) void gather_kernel(
    const float* __restrict__ x, const int* __restrict__ nbr,
    float* __restrict__ agg)
{
    int gid = blockIdx.x * 256 + threadIdx.x;   // < 32768*32
    int p = gid >> 5;
    int c4 = gid & 31;
    int b = p >> 11;
    const float* xb = x + (((size_t)b << 11) * HID);
    const int4* nr4 = (const int4*)(nbr + (size_t)p * KNN);
    int4 n0 = nr4[0], n1 = nr4[1], n2 = nr4[2], n3 = nr4[3];
    float4 s = make_float4(0.f, 0.f, 0.f, 0.f);
    int idx[16] = {n0.x, n0.y, n0.z, n0.w, n1.x, n1.y, n1.z, n1.w,
                   n2.x, n2.y, n2.z, n2.w, n3.x, n3.y, n3.z, n3.w};
    #pragma unroll
    for (int t = 0; t < 16; ++t) {
        float4 v = *(const float4*)&xb[(size_t)idx[t] * HID + c4 * 4];
        s.x += v.x; s.y += v.y; s.z += v.z; s.w += v.w;
    }
    *(float4*)&agg[(size_t)p * HID + c4 * 4] = s;
}

// ---------------------------------------------------------------------------
// GraphConv 128->128, v3.
// C[32768x128] = [agg|x] @ [Wr;Ws]^T + b.  Block: 64 points x all 128 h,
// 128 threads = m_t(8) x h_t(16); thread tile 8 points x 8 h (acc 64 regs).
// A staged TRANSPOSED in LDS As[k][point] (stride 68: b128-aligned,
// conflict-free reads via m_t broadcast, 2-way-free scatter writes).
// W read directly from global per k4 (L1-resident; each 16B feeds 32 FMAs).
// LDS:FMA-wall ratio = 96*nw/(512*nw/4) = 0.75 -> FMA-bound.
// 512 blocks = 2 blocks/CU for barrier overlap. Safe in-place.
// ---------------------------------------------------------------------------
template <bool RELU>
__global__ __launch_bounds__(128) void conv_kernel(
    const float* __restrict__ agg, const float* __restrict__ x,
    const float* __restrict__ Wr, const float* __restrict__ bias,
    const float* __restrict__ Ws, float* __restrict__ out)
{
    __shared__ __align__(16) float As[64][68];      // [k in chunk][point], 17.4 KB
    const int p0 = blockIdx.x * 64;
    const int m_t = threadIdx.x & 7;                // 8 point-groups
    const int h_t = threadIdx.x >> 3;               // 16 h-groups
    const int h0 = h_t * 8;

    float acc[8][8];                                // [point i][h j]
    #pragma unroll
    for (int i = 0; i < 8; ++i)
        #pragma unroll
        for (int j = 0; j < 8; ++j) acc[i][j] = 0.f;

    #pragma unroll 1
    for (int ch = 0; ch < 4; ++ch) {
        const float* src = (ch < 2 ? agg : x) + (size_t)p0 * HID + (ch & 1) * 64;
        const float* W = (ch < 2 ? Wr : Ws) + (ch & 1) * 64;
        __syncthreads();                            // protect As before overwrite
        // stage A chunk transposed: 64 points x 64 k.
        // lane -> distinct point row (scattered global, L2-fast; LDS
        // writes hit distinct banks per lane -> conflict-free).
        #pragma unroll
        for (int it = 0; it < 8; ++it) {
            int idx = it * 128 + threadIdx.x;       // 0..1023 float4s
            int pp = idx & 63, kq = idx >> 6;       // kq 0..15
            float4 v = *(const float4*)&src[(size_t)pp * HID + kq * 4];
            As[kq * 4 + 0][pp] = v.x;
            As[kq * 4 + 1][pp] = v.y;
            As[kq * 4 + 2][pp] = v.z;
            As[kq * 4 + 3][pp] = v.w;
        }
        __syncthreads();

        #pragma unroll 2
        for (int k4 = 0; k4 < 16; ++k4) {
            float4 w[8];
            #pragma unroll
            for (int j = 0; j < 8; ++j)
                w[j] = *(const float4*)&W[(size_t)(h0 + j) * HID + k4 * 4];
            #pragma unroll
            for (int kk = 0; kk < 4; ++kk) {
                int krow = k4 * 4 + kk;
                float4 aA = *(const float4*)&As[krow][m_t * 4];
                float4 aB = *(const float4*)&As[krow][m_t * 4 + 32];
                float av[8] = {aA.x, aA.y, aA.z, aA.w, aB.x, aB.y, aB.z, aB.w};
                #pragma unroll
                for (int j = 0; j < 8; ++j) {
                    float wv = ((const float*)&w[j])[kk];
                    #pragma unroll
                    for (int i = 0; i < 8; ++i)
                        acc[i][j] = fmaf(av[i], wv, acc[i][j]);
                }
            }
        }
    }

    // epilogue: bias (+relu), write thread's 8 points x 8 h
    float4 b0 = *(const float4*)&bias[h0];
    float4 b1v = *(const float4*)&bias[h0 + 4];
    #pragma unroll
    for (int i = 0; i < 8; ++i) {
        int pi = m_t * 4 + (i & 3) + (i >> 2) * 32;
        float4 r0, r1;
        r0.x = acc[i][0] + b0.x;  r0.y = acc[i][1] + b0.y;
        r0.z = acc[i][2] + b0.z;  r0.w = acc[i][3] + b0.w;
        r1.x = acc[i][4] + b1v.x; r1.y = acc[i][5] + b1v.y;
        r1.z = acc[i][6] + b1v.z; r1.w = acc[i][7] + b1v.w;
        if (RELU) {
            r0.x = fmaxf(r0.x, 0.f); r0.y = fmaxf(r0.y, 0.f);
            r0.z = fmaxf(r0.z, 0.f); r0.w = fmaxf(r0.w, 0.f);
            r1.x = fmaxf(r1.x, 0.f); r1.y = fmaxf(r1.y, 0.f);
            r1.z = fmaxf(r1.z, 0.f); r1.w = fmaxf(r1.w, 0.f);
        }
        float* orow = &out[(size_t)(p0 + pi) * HID + h0];
        *(float4*)&orow[0] = r0;
        *(float4*)&orow[4] = r1;
    }
}

// ---------------------------------------------------------------------------
extern "C" void kernel_launch(void* const* d_in, const int* in_sizes, int n_in,
                              void* d_out, int out_size, void* d_ws, size_t ws_size,
                              hipStream_t stream)
{
    const float* pc  = (const float*)d_in[0];
    const float* W1r = (const float*)d_in[1];
    const float* b1  = (const float*)d_in[2];
    const float* W1s = (const float*)d_in[3];
    const float* W2r = (const float*)d_in[4];
    const float* b2  = (const float*)d_in[5];
    const float* W2s = (const float*)d_in[6];
    const float* W3r = (const float*)d_in[7];
    const float* b3  = (const float*)d_in[8];
    const float* W3s = (const float*)d_in[9];
    float* out = (float*)d_out;

    char* ws = (char*)d_ws;
    int*   nbr  = (int*)ws;                                   // 2 MB
    float* xbuf = (float*)(ws + (size_t)2 * 1024 * 1024);     // 16.78 MB
    float* aggb = (float*)(ws + (size_t)(2 * 1024 * 1024) + (size_t)BATCH * NPTS * HID * 4);

    const int NPOINTS = BATCH * NPTS;                         // 32768

    knn_kernel<<<NPOINTS / RPB, 512, 0, stream>>>(pc, nbr);
    layer1_kernel<<<NPOINTS, 128, 0, stream>>>(pc, nbr, W1r, b1, W1s, xbuf);

    gather_kernel<<<NPOINTS * 32 / 256, 256, 0, stream>>>(xbuf, nbr, aggb);
    conv_kernel<true><<<NPOINTS / 64, 128, 0, stream>>>(aggb, xbuf, W2r, b2, W2s, xbuf);

    gather_kernel<<<NPOINTS * 32 / 256, 256, 0, stream>>>(xbuf, nbr, aggb);
    conv_kernel<false><<<NPOINTS / 64, 128, 0, stream>>>(aggb, xbuf, W3r, b3, W3s, out);
}

// Round 5
// 198.829 us; speedup vs baseline: 1.4871x; 1.4871x over previous
//
#include <hip/hip_runtime.h>
#include <math.h>

#define NPTS 2048
#define BATCH 16
#define KNN 16
#define HID 128
#define RPB 8          // rows (queries) per block = waves per block
#define CAP 128        // compacted-candidate capacity per wave

typedef __attribute__((ext_vector_type(8))) short bf16x8;
typedef __attribute__((ext_vector_type(4))) float f32x4;

__device__ inline unsigned short f2bf(float f) {    // RNE f32 -> bf16 bits
    unsigned u = __float_as_uint(f);
    return (unsigned short)((u + 0x7FFFu + ((u >> 16) & 1u)) >> 16);
}
__device__ inline float bflo(unsigned v) { return __uint_as_float(v << 16); }
__device__ inline float bfhi(unsigned v) { return __uint_as_float(v & 0xFFFF0000u); }

// ---------------------------------------------------------------------------
// kNN via threshold selection. One wave per query row. (Unchanged from R1.)
// ---------------------------------------------------------------------------
__global__ __launch_bounds__(512) void knn_kernel(const float* __restrict__ pc,
                                                  int* __restrict__ nbr)
{
    __shared__ __align__(16) float4 pts[NPTS];        // x,y,z,|p|^2  (32 KB)
    __shared__ unsigned ckey[RPB][CAP];               // 4 KB
    __shared__ unsigned cidx[RPB][CAP];               // 4 KB

    const int b = blockIdx.x >> 8;                    // 256 blocks per batch
    const int rblk = blockIdx.x & 255;
    const float* p = pc + (size_t)b * NPTS * 3;

    for (int t = threadIdx.x; t < NPTS; t += 512) {
        float x = p[t * 3 + 0], y = p[t * 3 + 1], z = p[t * 3 + 2];
        pts[t] = make_float4(x, y, z, x * x + y * y + z * z);
    }
    __syncthreads();

    const int w = threadIdx.x >> 6;
    const int lane = threadIdx.x & 63;
    const int i = rblk * RPB + w;                     // query row in batch
    const float4 pi = pts[i];

    unsigned key[32];
    #pragma unroll
    for (int t = 0; t < 32; ++t) {
        float4 c = pts[t * 64 + lane];
        float dot = fmaf(pi.x, c.x, fmaf(pi.y, c.y, pi.z * c.z));
        float d2 = fmaf(-2.0f, dot, pi.w + c.w);
        key[t] = __float_as_uint(d2 + 16.0f);
    }

    unsigned km = 0xFFFFFFFFu;
    #pragma unroll
    for (int t = 0; t < 32; ++t) km = min(km, key[t]);

    unsigned v = km;
    #pragma unroll
    for (int k = 2; k <= 64; k <<= 1) {
        #pragma unroll
        for (int j = k >> 1; j > 0; j >>= 1) {
            unsigned o = (unsigned)__shfl_xor((int)v, j, 64);
            bool up = ((lane & k) == 0);
            bool lower = ((lane & j) == 0);
            unsigned mn = min(v, o), mx = max(v, o);
            v = (up == lower) ? mn : mx;
        }
    }
    const unsigned T0 = (unsigned)__shfl((int)v, 15, 64);

    unsigned base = 0;
    #pragma unroll 1
    for (int t = 0; t < 32; ++t) {
        bool pred = key[t] <= T0;
        unsigned long long mask = __ballot(pred);
        if (mask) {
            unsigned prefix = __builtin_amdgcn_mbcnt_hi(
                (unsigned)(mask >> 32),
                __builtin_amdgcn_mbcnt_lo((unsigned)mask, 0));
            unsigned pos = base + prefix;
            if (pred && pos < CAP) {
                ckey[w][pos] = key[t];
                cidx[w][pos] = (unsigned)(t * 64 + lane);
            }
            base += (unsigned)__popcll(mask);
        }
    }
    __threadfence_block();
    const int m = (int)base;

    int* out = nbr + ((size_t)b * NPTS + i) * KNN;

    if (m <= CAP) {
        unsigned k0 = (lane < m) ? ckey[w][lane] : 0xFFFFFFFFu;
        unsigned k1 = (lane + 64 < m) ? ckey[w][lane + 64] : 0xFFFFFFFFu;
        int r0 = 0, r1 = 0;
        if (m <= 64) {
            #pragma unroll 1
            for (int jj = 0; jj < m; ++jj) {
                unsigned kj = ckey[w][jj];
                r0 += (kj < k0) || (kj == k0 && jj < lane);
            }
        } else {
            #pragma unroll 1
            for (int jj = 0; jj < m; ++jj) {
                unsigned kj = ckey[w][jj];
                r0 += (kj < k0) || (kj == k0 && jj < lane);
                r1 += (kj < k1) || (kj == k1 && jj < lane + 64);
            }
        }
        if (lane < m && r0 < KNN) out[r0] = (int)cidx[w][lane];
        if (lane + 64 < m && r1 < KNN) out[r1] = (int)cidx[w][lane + 64];
    } else {
        unsigned T = 0;
        #pragma unroll 1
        for (int bit = 31; bit >= 0; --bit) {
            unsigned trial = T | (1u << bit);
            int cnt = 0;
            #pragma unroll
            for (int t = 0; t < 32; ++t) cnt += (key[t] < trial);
            #pragma unroll
            for (int off = 32; off; off >>= 1)
                cnt += __shfl_xor(cnt, off, 64);
            if (cnt < KNN) T = trial;
        }
        unsigned bs = 0;
        #pragma unroll 1
        for (int t = 0; t < 32; ++t) {
            bool p1 = key[t] < T;
            unsigned long long mask = __ballot(p1);
            if (mask) {
                unsigned prefix = __builtin_amdgcn_mbcnt_hi(
                    (unsigned)(mask >> 32),
                    __builtin_amdgcn_mbcnt_lo((unsigned)mask, 0));
                if (p1) out[bs + prefix] = t * 64 + lane;
                bs += (unsigned)__popcll(mask);
            }
        }
        #pragma unroll 1
        for (int t = 0; t < 32 && bs < KNN; ++t) {
            bool p2 = key[t] == T;
            unsigned long long mask = __ballot(p2);
            if (mask) {
                unsigned prefix = __builtin_amdgcn_mbcnt_hi(
                    (unsigned)(mask >> 32),
                    __builtin_amdgcn_mbcnt_lo((unsigned)mask, 0));
                unsigned pos = bs + prefix;
                if (p2 && pos < KNN) out[pos] = t * 64 + lane;
                bs += (unsigned)__popcll(mask);
            }
        }
    }
}

// ---------------------------------------------------------------------------
// Layer 1: 3 -> 128, fused gather+matvec+bias+relu -> bf16. One block/point.
// ---------------------------------------------------------------------------
__global__ __launch_bounds__(128) void layer1_kernel(
    const float* __restrict__ pc, const int* __restrict__ nbr,
    const float* __restrict__ W1r, const float* __restrict__ b1,
    const float* __restrict__ W1s, unsigned short* __restrict__ x1)
{
    __shared__ float agg[3], xi[3];
    __shared__ float nb[KNN][3];
    const int p = blockIdx.x;                   // global point id
    const int b = p >> 11;
    const float* pcb = pc + ((size_t)b << 11) * 3;
    const int h = threadIdx.x;
    if (h < KNN) {
        int j = nbr[(size_t)p * KNN + h];
        nb[h][0] = pcb[j * 3 + 0];
        nb[h][1] = pcb[j * 3 + 1];
        nb[h][2] = pcb[j * 3 + 2];
    }
    if (h >= KNN && h < KNN + 3) {
        int c = h - KNN;
        xi[c] = pc[(size_t)p * 3 + c];
    }
    __syncthreads();
    if (h < 3) {
        float s = 0.f;
        #pragma unroll
        for (int t = 0; t < KNN; ++t) s += nb[t][h];
        agg[h] = s;
    }
    __syncthreads();
    float acc = b1[h];
    #pragma unroll
    for (int c = 0; c < 3; ++c)
        acc += W1r[h * 3 + c] * agg[c] + W1s[h * 3 + c] * xi[c];
    x1[(size_t)p * HID + h] = f2bf(fmaxf(acc, 0.f));
}

// ---------------------------------------------------------------------------
// Weight conversion: 4 x [128x128] f32 -> bf16 (one-shot, ~65K elements).
// ---------------------------------------------------------------------------
__global__ __launch_bounds__(256) void wcvt_kernel(
    const float* __restrict__ a, const float* __restrict__ b,
    const float* __restrict__ c, const float* __restrict__ d,
    unsigned short* __restrict__ out)
{
    int g = blockIdx.x * 256 + threadIdx.x;       // < 65536
    int m = g >> 14;
    const float* s = (m == 0) ? a : (m == 1) ? b : (m == 2) ? c : d;
    out[g] = f2bf(s[g & 16383]);
}

// ---------------------------------------------------------------------------
// Gather-sum (bf16 in/out, f32 accumulate): thread (p, c8) sums 16 rows.
// ---------------------------------------------------------------------------
__global__ __launch_bounds__(256) void gather_kernel(
    const unsigned short* __restrict__ x, const int* __restrict__ nbr,
    unsigned short* __restrict__ agg)
{
    int gid = blockIdx.x * 256 + threadIdx.x;     // < 32768*16
    int p = gid >> 4;
    int c8 = gid & 15;
    int b = p >> 11;
    const unsigned short* xb = x + (((size_t)b << 11) * HID);
    const int4* nr4 = (const int4*)(nbr + (size_t)p * KNN);
    int4 n0 = nr4[0], n1 = nr4[1], n2 = nr4[2], n3 = nr4[3];
    int idx[16] = {n0.x, n0.y, n0.z, n0.w, n1.x, n1.y, n1.z, n1.w,
                   n2.x, n2.y, n2.z, n2.w, n3.x, n3.y, n3.z, n3.w};
    float s0 = 0, s1 = 0, s2 = 0, s3 = 0, s4 = 0, s5 = 0, s6 = 0, s7 = 0;
    #pragma unroll
    for (int t = 0; t < 16; ++t) {
        uint4 v = *(const uint4*)(xb + (size_t)idx[t] * HID + c8 * 8);
        s0 += bflo(v.x); s1 += bfhi(v.x);
        s2 += bflo(v.y); s3 += bfhi(v.y);
        s4 += bflo(v.z); s5 += bfhi(v.z);
        s6 += bflo(v.w); s7 += bfhi(v.w);
    }
    uint4 ov;
    ov.x = (unsigned)f2bf(s0) | ((unsigned)f2bf(s1) << 16);
    ov.y = (unsigned)f2bf(s2) | ((unsigned)f2bf(s3) << 16);
    ov.z = (unsigned)f2bf(s4) | ((unsigned)f2bf(s5) << 16);
    ov.w = (unsigned)f2bf(s6) | ((unsigned)f2bf(s7) << 16);
    *(uint4*)&agg[(size_t)p * HID + c8 * 8] = ov;
}

// ---------------------------------------------------------------------------
// GraphConv 128->128 via bf16 MFMA, f32 accumulate.
// out[p][h] = Wr@agg_p + Ws@x_p + b (+relu).
// Block 256 thr = 4 waves; block tile 64 pts x 64 h; wave tile 32x32
// (2x2 of mfma_f32_16x16x32_bf16). No LDS, no barriers — fragments
// straight from global (A rows 16B/lane contiguous; W L2/L1-resident).
// Layouts [measured m89/m91/m92]: A[m=lane&15][k=quad*8+j]; B^T same;
// D: col=lane&15, row=quad*4+reg.
// ---------------------------------------------------------------------------
template <bool RELU, bool OUT_BF16>
__global__ __launch_bounds__(256) void conv_mfma(
    const unsigned short* __restrict__ Agg, const unsigned short* __restrict__ X,
    const unsigned short* __restrict__ Wr, const unsigned short* __restrict__ Ws,
    const float* __restrict__ bias, void* __restrict__ outv)
{
    const int wv = threadIdx.x >> 6;
    const int lane = threadIdx.x & 63;
    const int pt0 = (blockIdx.x >> 1) * 64 + (wv & 1) * 32;
    const int h0 = (blockIdx.x & 1) * 64 + (wv >> 1) * 32;
    const int row = lane & 15;
    const int quad = lane >> 4;

    f32x4 acc00 = {0, 0, 0, 0}, acc01 = {0, 0, 0, 0};
    f32x4 acc10 = {0, 0, 0, 0}, acc11 = {0, 0, 0, 0};

    const unsigned short* a0p = Agg + (size_t)(pt0 + row) * HID + quad * 8;
    const unsigned short* a1p = Agg + (size_t)(pt0 + 16 + row) * HID + quad * 8;
    const unsigned short* x0p = X + (size_t)(pt0 + row) * HID + quad * 8;
    const unsigned short* x1p = X + (size_t)(pt0 + 16 + row) * HID + quad * 8;
    const unsigned short* r0p = Wr + (size_t)(h0 + row) * HID + quad * 8;
    const unsigned short* r1p = Wr + (size_t)(h0 + 16 + row) * HID + quad * 8;
    const unsigned short* s0p = Ws + (size_t)(h0 + row) * HID + quad * 8;
    const unsigned short* s1p = Ws + (size_t)(h0 + 16 + row) * HID + quad * 8;

    #pragma unroll
    for (int kc = 0; kc < 4; ++kc) {
        bf16x8 a0 = *(const bf16x8*)(a0p + kc * 32);
        bf16x8 a1 = *(const bf16x8*)(a1p + kc * 32);
        bf16x8 b0 = *(const bf16x8*)(r0p + kc * 32);
        bf16x8 b1 = *(const bf16x8*)(r1p + kc * 32);
        acc00 = __builtin_amdgcn_mfma_f32_16x16x32_bf16(a0, b0, acc00, 0, 0, 0);
        acc01 = __builtin_amdgcn_mfma_f32_16x16x32_bf16(a0, b1, acc01, 0, 0, 0);
        acc10 = __builtin_amdgcn_mfma_f32_16x16x32_bf16(a1, b0, acc10, 0, 0, 0);
        acc11 = __builtin_amdgcn_mfma_f32_16x16x32_bf16(a1, b1, acc11, 0, 0, 0);
    }
    #pragma unroll
    for (int kc = 0; kc < 4; ++kc) {
        bf16x8 a0 = *(const bf16x8*)(x0p + kc * 32);
        bf16x8 a1 = *(const bf16x8*)(x1p + kc * 32);
        bf16x8 b0 = *(const bf16x8*)(s0p + kc * 32);
        bf16x8 b1 = *(const bf16x8*)(s1p + kc * 32);
        acc00 = __builtin_amdgcn_mfma_f32_16x16x32_bf16(a0, b0, acc00, 0, 0, 0);
        acc01 = __builtin_amdgcn_mfma_f32_16x16x32_bf16(a0, b1, acc01, 0, 0, 0);
        acc10 = __builtin_amdgcn_mfma_f32_16x16x32_bf16(a1, b0, acc10, 0, 0, 0);
        acc11 = __builtin_amdgcn_mfma_f32_16x16x32_bf16(a1, b1, acc11, 0, 0, 0);
    }

    const float blo = bias[h0 + row];
    const float bhi = bias[h0 + 16 + row];
    #pragma unroll
    for (int r = 0; r < 4; ++r) {
        int plo = pt0 + quad * 4 + r;
        int phi = plo + 16;
        float v00 = acc00[r] + blo, v01 = acc01[r] + bhi;
        float v10 = acc10[r] + blo, v11 = acc11[r] + bhi;
        if (RELU) {
            v00 = fmaxf(v00, 0.f); v01 = fmaxf(v01, 0.f);
            v10 = fmaxf(v10, 0.f); v11 = fmaxf(v11, 0.f);
        }
        if (OUT_BF16) {
            unsigned short* o = (unsigned short*)outv;
            o[(size_t)plo * HID + h0 + row] = f2bf(v00);
            o[(size_t)plo * HID + h0 + 16 + row] = f2bf(v01);
            o[(size_t)phi * HID + h0 + row] = f2bf(v10);
            o[(size_t)phi * HID + h0 + 16 + row] = f2bf(v11);
        } else {
            float* o = (float*)outv;
            o[(size_t)plo * HID + h0 + row] = v00;
            o[(size_t)plo * HID + h0 + 16 + row] = v01;
            o[(size_t)phi * HID + h0 + row] = v10;
            o[(size_t)phi * HID + h0 + 16 + row] = v11;
        }
    }
}

// ---------------------------------------------------------------------------
extern "C" void kernel_launch(void* const* d_in, const int* in_sizes, int n_in,
                              void* d_out, int out_size, void* d_ws, size_t ws_size,
                              hipStream_t stream)
{
    const float* pc  = (const float*)d_in[0];
    const float* W1r = (const float*)d_in[1];
    const float* b1  = (const float*)d_in[2];
    const float* W1s = (const float*)d_in[3];
    const float* W2r = (const float*)d_in[4];
    const float* b2  = (const float*)d_in[5];
    const float* W2s = (const float*)d_in[6];
    const float* W3r = (const float*)d_in[7];
    const float* b3  = (const float*)d_in[8];
    const float* W3s = (const float*)d_in[9];
    float* out = (float*)d_out;

    char* ws = (char*)d_ws;
    const size_t MB = 1024 * 1024;
    int*            nbr = (int*)ws;                              // 2 MB
    unsigned short* x1  = (unsigned short*)(ws + 2 * MB);        // 8.39 MB
    unsigned short* agg = (unsigned short*)(ws + 2 * MB + 8388608);
    unsigned short* x2  = (unsigned short*)(ws + 2 * MB + 2 * 8388608);
    unsigned short* wbf = (unsigned short*)(ws + 2 * MB + 3 * 8388608);
    unsigned short* w2r = wbf;
    unsigned short* w2s = wbf + 16384;
    unsigned short* w3r = wbf + 32768;
    unsigned short* w3s = wbf + 49152;

    const int NPOINTS = BATCH * NPTS;                            // 32768

    knn_kernel<<<NPOINTS / RPB, 512, 0, stream>>>(pc, nbr);
    layer1_kernel<<<NPOINTS, 128, 0, stream>>>(pc, nbr, W1r, b1, W1s, x1);
    wcvt_kernel<<<256, 256, 0, stream>>>(W2r, W2s, W3r, W3s, wbf);

    gather_kernel<<<NPOINTS * 16 / 256, 256, 0, stream>>>(x1, nbr, agg);
    conv_mfma<true, true><<<NPOINTS / 64 * 2, 256, 0, stream>>>(
        agg, x1, w2r, w2s, b2, x2);

    gather_kernel<<<NPOINTS * 16 / 256, 256, 0, stream>>>(x2, nbr, agg);
    conv_mfma<false, false><<<NPOINTS / 64 * 2, 256, 0, stream>>>(
        agg, x2, w3r, w3s, b3, out);
}